// Round 10
// baseline (77.537 us; speedup 1.0000x reference)
//
#include <hip/hip_runtime.h>

constexpr int   BATCH        = 16384;
constexpr int   CELLS        = 802816;            // BATCH * 49
constexpr int   F            = 30;
constexpr int   CPT          = 64;                // cells per wave-tile
constexpr int   NTILES       = CELLS / CPT;       // 12544 = 1792 * 7 exactly
constexpr int   TFL          = CPT * F;           // 1920 floats per input per tile
constexpr int   GRID         = 448;               // 448 blocks x 4 waves = 1792 waves
constexpr int   WPB          = 4;                 // waves per block (256 threads)
constexpr int   NWAVES       = GRID * WPB;        // 1792 -> exactly 7 tiles per wave
constexpr float LAMBDA_COORD = 5.0f;
constexpr float LAMBDA_NOOBJ = 0.5f;
constexpr float EPS_WH       = 1e-6f;
constexpr float EPS_IOU      = 1e-6f;

__device__ __forceinline__ float iou_yolo(const float b0, const float b1,
                                          const float b2, const float b3,
                                          const float c0, const float c1,
                                          const float c2, const float c3) {
    float b1x1 = b0 - b2 * 0.5f;
    float b1y1 = b1 - b3 * 0.5f;
    float b1x2 = b0 + b2 * 0.5f;
    float b1y2 = b1 + b3 * 0.5f;
    float b2x1 = c0 - c2 * 0.5f;
    float b2y1 = c1 - c3 * 0.5f;
    float b2x2 = c0 + c2 * 0.5f;
    float b2y2 = c1 + c3 * 0.5f;
    float iw = fmaxf(fminf(b1x2, b2x2) - fmaxf(b1x1, b2x1), 0.0f);
    float ih = fmaxf(fminf(b1y2, b2y2) - fmaxf(b1y1, b2y1), 0.0f);
    float inter = iw * ih;
    float a1 = fabsf((b1x2 - b1x1) * (b1y2 - b1y1));
    float a2 = fabsf((b2x2 - b2x1) * (b2y2 - b2y1));
    return inter / (a1 + a2 - inter + EPS_IOU);
}

__global__ void __launch_bounds__(256, 2)
yolo_loss_kernel(const float* __restrict__ yt_g,
                 const float* __restrict__ yp_g,
                 float* __restrict__ out) {
    // Wave-private single-buffered tile pairs: [wave][input][1920 floats] = 61440 B.
    __shared__ __align__(16) float lbuf[WPB][2][TFL];

    const int tid  = threadIdx.x;
    const int lane = tid & 63;
    const int wid  = tid >> 6;
    const int wgid = blockIdx.x * WPB + wid;   // global wave id, 0..1791

    // Per input per tile: 1920 floats = 448 float4 (7/lane) + 64 float2 (1/lane).
    const float4* tg4 = reinterpret_cast<const float4*>(yt_g);
    const float4* pg4 = reinterpret_cast<const float4*>(yp_g);
    const float2* tg2 = reinterpret_cast<const float2*>(yt_g);
    const float2* pg2 = reinterpret_cast<const float2*>(yp_g);
    float4* lt4 = reinterpret_cast<float4*>(lbuf[wid][0]);
    float4* lp4 = reinterpret_cast<float4*>(lbuf[wid][1]);
    float2* lt2 = reinterpret_cast<float2*>(lbuf[wid][0]);
    float2* lp2 = reinterpret_cast<float2*>(lbuf[wid][1]);

    float4 rt[7], rp[7];
    float2 st, sp;

    // ---- Prologue: load tile0 to VGPRs (coalesced dwordx4), write to LDS ----
    int tile = wgid;
    {
        const size_t b4 = (size_t)tile * (TFL / 4);
        const size_t b2 = (size_t)tile * (TFL / 2);
#pragma unroll
        for (int j = 0; j < 7; ++j) {
            rt[j] = tg4[b4 + lane + 64 * j];
            rp[j] = pg4[b4 + lane + 64 * j];
        }
        st = tg2[b2 + 896 + lane];
        sp = pg2[b2 + 896 + lane];
#pragma unroll
        for (int j = 0; j < 7; ++j) {
            lt4[lane + 64 * j] = rt[j];
            lp4[lane + 64 * j] = rp[j];
        }
        lt2[896 + lane] = st;
        lp2[896 + lane] = sp;
    }

    float acc = 0.0f;

    for (; tile < NTILES; tile += NWAVES) {
        const int next = tile + NWAVES;
        if (next < NTILES) {                   // wave-uniform branch
            // Issue next tile's coalesced loads into VGPRs — no wait yet.
            const size_t b4 = (size_t)next * (TFL / 4);
            const size_t b2 = (size_t)next * (TFL / 2);
#pragma unroll
            for (int j = 0; j < 7; ++j) {
                rt[j] = tg4[b4 + lane + 64 * j];
                rp[j] = pg4[b4 + lane + 64 * j];
            }
            st = tg2[b2 + 896 + lane];
            sp = pg2[b2 + 896 + lane];
        }

        // ---- Compute current tile from LDS (wave-private, no barrier) ----
        const float2* t2 = reinterpret_cast<const float2*>(&lbuf[wid][0][lane * F]);
        const float2* p2 = reinterpret_cast<const float2*>(&lbuf[wid][1][lane * F]);
        float t[F], p[F];
        {   // t: channels 0..4 and 10..29 (5..9 dead)
            float2 v;
            v = t2[0]; t[0] = v.x; t[1] = v.y;
            v = t2[1]; t[2] = v.x; t[3] = v.y;
            v = t2[2]; t[4] = v.x;
#pragma unroll
            for (int k = 5; k < 15; ++k) { v = t2[k]; t[2 * k] = v.x; t[2 * k + 1] = v.y; }
        }
#pragma unroll
        for (int k = 0; k < 15; ++k) { float2 w = p2[k]; p[2 * k] = w.x; p[2 * k + 1] = w.y; }

        const float objf   = (t[4] == 1.0f) ? 1.0f : 0.0f;
        const float noobjf = 1.0f - objf;

        const float iou1 = iou_yolo(t[0], t[1], t[2], t[3], p[0], p[1], p[2], p[3]);
        const float iou2 = iou_yolo(t[0], t[1], t[2], t[3], p[5], p[6], p[7], p[8]);
        const bool  best1 = iou1 > iou2;

        const float bh0 = best1 ? p[0] : p[5];
        const float bh1 = best1 ? p[1] : p[6];
        const float bh2 = best1 ? p[2] : p[7];
        const float bh3 = best1 ? p[3] : p[8];
        const float confhat = best1 ? p[4] : p[9];

        const float dx = t[0] - bh0;
        const float dy = t[1] - bh1;
        const float xy = dx * dx + dy * dy;

        const float wt = sqrtf(t[2]) - sqrtf(fabsf(bh2 + EPS_WH));
        const float ht = sqrtf(t[3]) - sqrtf(fabsf(bh3 + EPS_WH));
        const float wh = wt * wt + ht * ht;

        const float dc = t[4] - confhat;

        float cls = 0.0f;
#pragma unroll
        for (int c = 10; c < F; ++c) {
            const float d = t[c] - p[c];
            cls += d * d;
        }
        // noobj: reference slices yp[..., 4::5] -> channels 4,9,14,19,24,29
        float noobj = 0.0f;
#pragma unroll
        for (int c = 4; c < F; c += 5) {
            const float d = t[4] - p[c];
            noobj += d * d;
        }

        acc += objf * (LAMBDA_COORD * (xy + wh) + dc * dc + cls)
             + noobjf * (LAMBDA_NOOBJ * noobj);

        if (next < NTILES) {
            // Current-tile ds_reads all retired; fence, then overwrite the
            // single buffer with the prefetched next tile.
            asm volatile("s_waitcnt lgkmcnt(0)" ::: "memory");
            asm volatile("s_waitcnt vmcnt(0)" ::: "memory");
#pragma unroll
            for (int j = 0; j < 7; ++j) {
                lt4[lane + 64 * j] = rt[j];
                lp4[lane + 64 * j] = rp[j];
            }
            lt2[896 + lane] = st;
            lp2[896 + lane] = sp;
        }
    }

    // ---- Wave shuffle reduction -> block LDS -> one atomic per block ----
#pragma unroll
    for (int off = 32; off > 0; off >>= 1) acc += __shfl_down(acc, off);

    __shared__ float wsum[WPB];
    if (lane == 0) wsum[wid] = acc;
    __syncthreads();
    if (tid == 0) {
        float s = 0.0f;
#pragma unroll
        for (int w = 0; w < WPB; ++w) s += wsum[w];
        atomicAdd(out, s * (1.0f / (float)BATCH));
    }
}

extern "C" void kernel_launch(void* const* d_in, const int* in_sizes, int n_in,
                              void* d_out, int out_size, void* d_ws, size_t ws_size,
                              hipStream_t stream) {
    const float* y_trues = (const float*)d_in[0];
    const float* y_preds = (const float*)d_in[1];
    float* out = (float*)d_out;

    // Harness poisons d_out once, never re-poisons between replays: zero it every call.
    hipMemsetAsync(out, 0, sizeof(float) * (size_t)out_size, stream);

    yolo_loss_kernel<<<GRID, 256, 0, stream>>>(y_trues, y_preds, out);
}

// Round 11
// 37.871 us; speedup vs baseline: 2.0474x; 2.0474x over previous
//
#include <hip/hip_runtime.h>

constexpr int   BATCH        = 16384;
constexpr int   CELLS        = 802816;            // BATCH * 49
constexpr int   F            = 30;
constexpr int   CPT          = 64;                // cells per wave-tile
constexpr int   NTILES       = CELLS / CPT;       // 12544 = 1792 * 7 exactly
constexpr int   TFL2         = CPT * F / 2;       // 960 float2 per input per tile
constexpr int   GRID         = 448;               // 448 blocks x 4 waves = 1792 waves
constexpr int   WPB          = 4;                 // waves per block (256 threads)
constexpr int   NWAVES       = GRID * WPB;        // 1792 -> exactly 7 tiles per wave
constexpr float LAMBDA_COORD = 5.0f;
constexpr float LAMBDA_NOOBJ = 0.5f;
constexpr float EPS_WH       = 1e-6f;
constexpr float EPS_IOU      = 1e-6f;

__device__ __forceinline__ float iou_yolo(const float b0, const float b1,
                                          const float b2, const float b3,
                                          const float c0, const float c1,
                                          const float c2, const float c3) {
    float b1x1 = b0 - b2 * 0.5f;
    float b1y1 = b1 - b3 * 0.5f;
    float b1x2 = b0 + b2 * 0.5f;
    float b1y2 = b1 + b3 * 0.5f;
    float b2x1 = c0 - c2 * 0.5f;
    float b2y1 = c1 - c3 * 0.5f;
    float b2x2 = c0 + c2 * 0.5f;
    float b2y2 = c1 + c3 * 0.5f;
    float iw = fmaxf(fminf(b1x2, b2x2) - fmaxf(b1x1, b2x1), 0.0f);
    float ih = fmaxf(fminf(b1y2, b2y2) - fmaxf(b1y1, b2y1), 0.0f);
    float inter = iw * ih;
    float a1 = fabsf((b1x2 - b1x1) * (b1y2 - b1y1));
    float a2 = fabsf((b2x2 - b2x1) * (b2y2 - b2y1));
    return inter / (a1 + a2 - inter + EPS_IOU);
}

__global__ void __launch_bounds__(256, 2)
yolo_loss_kernel(const float* __restrict__ yt_g,
                 const float* __restrict__ yp_g,
                 float* __restrict__ out) {
    // Wave-private SINGLE-buffered tile pairs: [wave][input][1920 floats] = 61440 B.
    __shared__ __align__(16) float lbuf[WPB][2][CPT * F];

    const int tid  = threadIdx.x;
    const int lane = tid & 63;
    const int wid  = tid >> 6;
    const int wgid = blockIdx.x * WPB + wid;   // global wave id, 0..1791

    const float2* tg2 = reinterpret_cast<const float2*>(yt_g);
    const float2* pg2 = reinterpret_cast<const float2*>(yp_g);
    float2* lt2 = reinterpret_cast<float2*>(lbuf[wid][0]);
    float2* lp2 = reinterpret_cast<float2*>(lbuf[wid][1]);

    // float2 staging arrays: proven spill-free (R9: WRITE_SIZE=16B, VGPR=88).
    // Do NOT switch to float4[7] — R10 spilled 155 MB to scratch.
    float2 rt[15], rp[15];

    // ---- Prologue: load tile0 to VGPRs (coalesced), write to this wave's LDS ----
    int tile = wgid;
    {
        const size_t b2i = (size_t)tile * TFL2;
#pragma unroll
        for (int j = 0; j < 15; ++j) {
            rt[j] = tg2[b2i + lane + 64 * j];
            rp[j] = pg2[b2i + lane + 64 * j];
        }
#pragma unroll
        for (int j = 0; j < 15; ++j) {
            lt2[lane + 64 * j] = rt[j];
            lp2[lane + 64 * j] = rp[j];
        }
    }

    float acc = 0.0f;

    for (; tile < NTILES; tile += NWAVES) {
        const int next = tile + NWAVES;
        if (next < NTILES) {                   // wave-uniform branch
            // Issue next tile's coalesced loads into VGPRs — no wait yet.
            const size_t b2i = (size_t)next * TFL2;
#pragma unroll
            for (int j = 0; j < 15; ++j) {
                rt[j] = tg2[b2i + lane + 64 * j];
                rp[j] = pg2[b2i + lane + 64 * j];
            }
        }

        // ---- Compute current tile from LDS (wave-private, no barrier) ----
        const float2* t2 = reinterpret_cast<const float2*>(&lbuf[wid][0][lane * F]);
        const float2* p2 = reinterpret_cast<const float2*>(&lbuf[wid][1][lane * F]);
        float t[F], p[F];
        {   // t: channels 0..4 and 10..29 (5..9 dead)
            float2 v;
            v = t2[0]; t[0] = v.x; t[1] = v.y;
            v = t2[1]; t[2] = v.x; t[3] = v.y;
            v = t2[2]; t[4] = v.x;
#pragma unroll
            for (int k = 5; k < 15; ++k) { v = t2[k]; t[2 * k] = v.x; t[2 * k + 1] = v.y; }
        }
#pragma unroll
        for (int k = 0; k < 15; ++k) { float2 w = p2[k]; p[2 * k] = w.x; p[2 * k + 1] = w.y; }

        const float objf   = (t[4] == 1.0f) ? 1.0f : 0.0f;
        const float noobjf = 1.0f - objf;

        const float iou1 = iou_yolo(t[0], t[1], t[2], t[3], p[0], p[1], p[2], p[3]);
        const float iou2 = iou_yolo(t[0], t[1], t[2], t[3], p[5], p[6], p[7], p[8]);
        const bool  best1 = iou1 > iou2;

        const float bh0 = best1 ? p[0] : p[5];
        const float bh1 = best1 ? p[1] : p[6];
        const float bh2 = best1 ? p[2] : p[7];
        const float bh3 = best1 ? p[3] : p[8];
        const float confhat = best1 ? p[4] : p[9];

        const float dx = t[0] - bh0;
        const float dy = t[1] - bh1;
        const float xy = dx * dx + dy * dy;

        const float wt = sqrtf(t[2]) - sqrtf(fabsf(bh2 + EPS_WH));
        const float ht = sqrtf(t[3]) - sqrtf(fabsf(bh3 + EPS_WH));
        const float wh = wt * wt + ht * ht;

        const float dc = t[4] - confhat;

        float cls = 0.0f;
#pragma unroll
        for (int c = 10; c < F; ++c) {
            const float d = t[c] - p[c];
            cls += d * d;
        }
        // noobj: reference slices yp[..., 4::5] -> channels 4,9,14,19,24,29
        float noobj = 0.0f;
#pragma unroll
        for (int c = 4; c < F; c += 5) {
            const float d = t[4] - p[c];
            noobj += d * d;
        }

        acc += objf * (LAMBDA_COORD * (xy + wh) + dc * dc + cls)
             + noobjf * (LAMBDA_NOOBJ * noobj);

        if (next < NTILES) {
            // All current-tile ds_reads retired (their data fed acc); fence then
            // overwrite the single buffer with the prefetched next tile.
            asm volatile("s_waitcnt lgkmcnt(0)" ::: "memory");
            asm volatile("s_waitcnt vmcnt(0)" ::: "memory");
#pragma unroll
            for (int j = 0; j < 15; ++j) {
                lt2[lane + 64 * j] = rt[j];
                lp2[lane + 64 * j] = rp[j];
            }
        }
    }

    // ---- Wave shuffle reduction -> block LDS -> one atomic per block ----
#pragma unroll
    for (int off = 32; off > 0; off >>= 1) acc += __shfl_down(acc, off);

    __shared__ float wsum[WPB];
    if (lane == 0) wsum[wid] = acc;
    __syncthreads();
    if (tid == 0) {
        float s = 0.0f;
#pragma unroll
        for (int w = 0; w < WPB; ++w) s += wsum[w];
        atomicAdd(out, s * (1.0f / (float)BATCH));
    }
}

extern "C" void kernel_launch(void* const* d_in, const int* in_sizes, int n_in,
                              void* d_out, int out_size, void* d_ws, size_t ws_size,
                              hipStream_t stream) {
    const float* y_trues = (const float*)d_in[0];
    const float* y_preds = (const float*)d_in[1];
    float* out = (float*)d_out;

    // Harness poisons d_out once, never re-poisons between replays: zero it every call.
    hipMemsetAsync(out, 0, sizeof(float) * (size_t)out_size, stream);

    yolo_loss_kernel<<<GRID, 256, 0, stream>>>(y_trues, y_preds, out);
}

// Round 12
// 33.932 us; speedup vs baseline: 2.2851x; 1.1161x over previous
//
#include <hip/hip_runtime.h>

constexpr int   BATCH        = 16384;
constexpr int   CELLS        = 802816;            // BATCH * 49
constexpr int   F            = 30;
constexpr int   CPT          = 64;                // cells per wave-tile
constexpr int   NTILES       = CELLS / CPT;       // 12544 = 1792 * 7 exactly
constexpr int   TFL2         = CPT * F / 2;       // 960 float2 per input per tile
constexpr int   GRID         = 448;               // 448 blocks x 4 waves = 1792 waves
constexpr int   WPB          = 4;                 // waves per block (256 threads)
constexpr int   NWAVES       = GRID * WPB;        // 1792 -> exactly 7 tiles per wave
constexpr float LAMBDA_COORD = 5.0f;
constexpr float LAMBDA_NOOBJ = 0.5f;
constexpr float EPS_WH       = 1e-6f;
constexpr float EPS_IOU      = 1e-6f;

__device__ __forceinline__ float iou_yolo(const float b0, const float b1,
                                          const float b2, const float b3,
                                          const float c0, const float c1,
                                          const float c2, const float c3) {
    float b1x1 = b0 - b2 * 0.5f;
    float b1y1 = b1 - b3 * 0.5f;
    float b1x2 = b0 + b2 * 0.5f;
    float b1y2 = b1 + b3 * 0.5f;
    float b2x1 = c0 - c2 * 0.5f;
    float b2y1 = c1 - c3 * 0.5f;
    float b2x2 = c0 + c2 * 0.5f;
    float b2y2 = c1 + c3 * 0.5f;
    float iw = fmaxf(fminf(b1x2, b2x2) - fmaxf(b1x1, b2x1), 0.0f);
    float ih = fmaxf(fminf(b1y2, b2y2) - fmaxf(b1y1, b2y1), 0.0f);
    float inter = iw * ih;
    float a1 = fabsf((b1x2 - b1x1) * (b1y2 - b1y1));
    float a2 = fabsf((b2x2 - b2x1) * (b2y2 - b2y1));
    return inter / (a1 + a2 - inter + EPS_IOU);
}

__global__ void __launch_bounds__(256, 2)
yolo_loss_kernel(const float* __restrict__ yt_g,
                 const float* __restrict__ yp_g,
                 float* __restrict__ ws) {
    // Wave-private SINGLE-buffered tile pairs: [wave][input][1920 floats] = 61440 B.
    __shared__ __align__(16) float lbuf[WPB][2][CPT * F];

    const int tid  = threadIdx.x;
    const int lane = tid & 63;
    const int wid  = tid >> 6;
    const int wgid = blockIdx.x * WPB + wid;   // global wave id, 0..1791

    const float2* tg2 = reinterpret_cast<const float2*>(yt_g);
    const float2* pg2 = reinterpret_cast<const float2*>(yp_g);
    float2* lt2 = reinterpret_cast<float2*>(lbuf[wid][0]);
    float2* lp2 = reinterpret_cast<float2*>(lbuf[wid][1]);

    // float2 staging arrays: proven spill-free (R9/R11: WRITE_SIZE~16B, VGPR=88).
    // Do NOT switch to float4[7] — R10 spilled 155 MB to scratch.
    float2 rt[15], rp[15];

    // ---- Prologue: load tile0 to VGPRs (coalesced), write to this wave's LDS ----
    int tile = wgid;
    {
        const size_t b2i = (size_t)tile * TFL2;
#pragma unroll
        for (int j = 0; j < 15; ++j) {
            rt[j] = tg2[b2i + lane + 64 * j];
            rp[j] = pg2[b2i + lane + 64 * j];
        }
#pragma unroll
        for (int j = 0; j < 15; ++j) {
            lt2[lane + 64 * j] = rt[j];
            lp2[lane + 64 * j] = rp[j];
        }
    }

    float acc = 0.0f;

    for (; tile < NTILES; tile += NWAVES) {
        const int next = tile + NWAVES;
        if (next < NTILES) {                   // wave-uniform branch
            // Issue next tile's coalesced loads into VGPRs — no wait yet.
            const size_t b2i = (size_t)next * TFL2;
#pragma unroll
            for (int j = 0; j < 15; ++j) {
                rt[j] = tg2[b2i + lane + 64 * j];
                rp[j] = pg2[b2i + lane + 64 * j];
            }
        }

        // ---- Compute current tile from LDS (wave-private, no barrier) ----
        const float2* t2 = reinterpret_cast<const float2*>(&lbuf[wid][0][lane * F]);
        const float2* p2 = reinterpret_cast<const float2*>(&lbuf[wid][1][lane * F]);
        float t[F], p[F];
        {   // t: channels 0..4 and 10..29 (5..9 dead)
            float2 v;
            v = t2[0]; t[0] = v.x; t[1] = v.y;
            v = t2[1]; t[2] = v.x; t[3] = v.y;
            v = t2[2]; t[4] = v.x;
#pragma unroll
            for (int k = 5; k < 15; ++k) { v = t2[k]; t[2 * k] = v.x; t[2 * k + 1] = v.y; }
        }
#pragma unroll
        for (int k = 0; k < 15; ++k) { float2 w = p2[k]; p[2 * k] = w.x; p[2 * k + 1] = w.y; }

        const float objf   = (t[4] == 1.0f) ? 1.0f : 0.0f;
        const float noobjf = 1.0f - objf;

        const float iou1 = iou_yolo(t[0], t[1], t[2], t[3], p[0], p[1], p[2], p[3]);
        const float iou2 = iou_yolo(t[0], t[1], t[2], t[3], p[5], p[6], p[7], p[8]);
        const bool  best1 = iou1 > iou2;

        const float bh0 = best1 ? p[0] : p[5];
        const float bh1 = best1 ? p[1] : p[6];
        const float bh2 = best1 ? p[2] : p[7];
        const float bh3 = best1 ? p[3] : p[8];
        const float confhat = best1 ? p[4] : p[9];

        const float dx = t[0] - bh0;
        const float dy = t[1] - bh1;
        const float xy = dx * dx + dy * dy;

        const float wt = sqrtf(t[2]) - sqrtf(fabsf(bh2 + EPS_WH));
        const float ht = sqrtf(t[3]) - sqrtf(fabsf(bh3 + EPS_WH));
        const float wh = wt * wt + ht * ht;

        const float dc = t[4] - confhat;

        float cls = 0.0f;
#pragma unroll
        for (int c = 10; c < F; ++c) {
            const float d = t[c] - p[c];
            cls += d * d;
        }
        // noobj: reference slices yp[..., 4::5] -> channels 4,9,14,19,24,29
        float noobj = 0.0f;
#pragma unroll
        for (int c = 4; c < F; c += 5) {
            const float d = t[4] - p[c];
            noobj += d * d;
        }

        acc += objf * (LAMBDA_COORD * (xy + wh) + dc * dc + cls)
             + noobjf * (LAMBDA_NOOBJ * noobj);

        if (next < NTILES) {
            // All current-tile ds_reads retired (their data fed acc); fence then
            // overwrite the single buffer with the prefetched next tile.
            asm volatile("s_waitcnt lgkmcnt(0)" ::: "memory");
            asm volatile("s_waitcnt vmcnt(0)" ::: "memory");
#pragma unroll
            for (int j = 0; j < 15; ++j) {
                lt2[lane + 64 * j] = rt[j];
                lp2[lane + 64 * j] = rp[j];
            }
        }
    }

    // ---- Wave shuffle reduction -> block LDS -> ONE PLAIN STORE per block ----
    // Every ws slot is overwritten every call: no zeroing, no atomics, no memset node.
#pragma unroll
    for (int off = 32; off > 0; off >>= 1) acc += __shfl_down(acc, off);

    __shared__ float wsum[WPB];
    if (lane == 0) wsum[wid] = acc;
    __syncthreads();
    if (tid == 0) {
        float s = 0.0f;
#pragma unroll
        for (int w = 0; w < WPB; ++w) s += wsum[w];
        ws[blockIdx.x] = s;
    }
}

__global__ void __launch_bounds__(256)
yolo_finalize_kernel(const float* __restrict__ ws, float* __restrict__ out) {
    const int tid = threadIdx.x;
    // 448 partials: tid<192 reads two, else one.
    float s = ws[tid];
    if (tid < GRID - 256) s += ws[tid + 256];
#pragma unroll
    for (int off = 32; off > 0; off >>= 1) s += __shfl_down(s, off);

    __shared__ float wsum[4];
    const int lane = tid & 63;
    const int wid  = tid >> 6;
    if (lane == 0) wsum[wid] = s;
    __syncthreads();
    if (tid == 0) out[0] = (wsum[0] + wsum[1] + wsum[2] + wsum[3]) * (1.0f / (float)BATCH);
}

extern "C" void kernel_launch(void* const* d_in, const int* in_sizes, int n_in,
                              void* d_out, int out_size, void* d_ws, size_t ws_size,
                              hipStream_t stream) {
    const float* y_trues = (const float*)d_in[0];
    const float* y_preds = (const float*)d_in[1];
    float* out = (float*)d_out;
    float* ws  = (float*)d_ws;

    yolo_loss_kernel<<<GRID, 256, 0, stream>>>(y_trues, y_preds, ws);
    yolo_finalize_kernel<<<1, 256, 0, stream>>>(ws, out);
}